// Round 8
// baseline (2274.533 us; speedup 1.0000x reference)
//
#include <hip/hip_runtime.h>
#include <hip/hip_bf16.h>
#include <cstdint>

#define Bn 8
#define Hh 256
#define Ww 256
#define HW 65536
#define SDIM 64
#define LABELS 35
#define NHID 128
// channel-last tensor: [h][octet(16)][px(256)] of 16B units; bytes per batch:
#define CLB ((size_t)Hh * 16 * 256 * 16)

typedef __attribute__((ext_vector_type(8))) short bf16x8;   // 8 bf16 = one A/B k-octet
typedef __attribute__((ext_vector_type(4))) float f32x4;    // MFMA C/D frag
#define MFMA16 __builtin_amdgcn_mfma_f32_16x16x32_bf16

// ---- async global->LDS 16B copy (used only by repack_fin staging) ----
__device__ __forceinline__ void gll16(const void* g, void* l) {
    __builtin_amdgcn_global_load_lds(
        (__attribute__((address_space(1))) const void*)(uintptr_t)g,
        (__attribute__((address_space(3))) void*)(uint32_t)(uintptr_t)l, 16, 0, 0);
}

// ---- per-lane global B-fragment read (no LDS): lane l -> octet l>>4 of chunk,
// px = wv*64 + pt*16 + (l&15) + kx - 1 ; OOB rows/cols -> zrow (16B of zeros)
__device__ __forceinline__ bf16x8 breadG(const char* rowp, bool rok, int px,
                                         const char* zp) {
    bool ok = rok && ((unsigned)px < Ww);
    const char* src = ok ? rowp + (size_t)px * 16 : zp;
    return *(const bf16x8*)src;
}

__device__ __forceinline__ bf16x8 aread(const ushort* base, int blk, int loff) {
    return *(const bf16x8*)((const char*)base + ((size_t)blk << 10) + loff);
}
// wfC block index: mats 0=w1hi 1=w1lo 2=w0hi 3=w0lo ; half = ic-half (0:0-31,1:32-63)
__device__ __forceinline__ int blkC(int ocbI, int mat, int half, int tap) {
    return (((ocbI * 4 + mat) * 2 + half) * 9 + tap);
}

// ---------------- repack: fin fp32 [b][ic][h][w] -> finCL hi/lo bf16 ---------
__global__ __launch_bounds__(256) void repack_fin(
    const float* __restrict__ fin, char* __restrict__ fincl, int batch0)
{
    __shared__ __align__(16) float fs[64 * 256];
    const int t = threadIdx.x, h = blockIdx.x, z = blockIdx.y;
    const int b = batch0 + z;
    const int wv = t >> 6, l = t & 63;
    const float* finb = fin + (size_t)b * 64 * HW + (size_t)h * 256;
#pragma unroll
    for (int i = 0; i < 16; i++) {
        int ic = wv * 16 + i;
        gll16(finb + (size_t)ic * HW + l * 4, fs + ic * 256);
    }
    __syncthreads();
    char* outb = fincl + (size_t)z * CLB + (size_t)h * 16 * 256 * 16;
#pragma unroll
    for (int jo = 0; jo < 8; jo++) {
        uint hi[4], lo[4];
#pragma unroll
        for (int c = 0; c < 8; c += 2) {
            float v0 = fs[(jo * 8 + c) * 256 + t];
            float v1 = fs[(jo * 8 + c + 1) * 256 + t];
            __hip_bfloat16 h0 = __float2bfloat16(v0), h1 = __float2bfloat16(v1);
            float r0 = v0 - __bfloat162float(h0), r1 = v1 - __bfloat162float(h1);
            __hip_bfloat16 l0 = __float2bfloat16(r0), l1 = __float2bfloat16(r1);
            hi[c >> 1] = (uint)*(ushort*)&h0 | ((uint)*(ushort*)&h1 << 16);
            lo[c >> 1] = (uint)*(ushort*)&l0 | ((uint)*(ushort*)&l1 << 16);
        }
        *(uint4*)(outb + ((size_t)jo * 256 + t) * 16)       = make_uint4(hi[0], hi[1], hi[2], hi[3]);
        *(uint4*)(outb + ((size_t)(jo + 8) * 256 + t) * 16) = make_uint4(lo[0], lo[1], lo[2], lo[3]);
    }
}

// ---------------- A-frag prep for w1 (w_conv) and w0 (w_c0), hi/lo ----------
__global__ void prep_wfragC(const float* __restrict__ w1, const float* __restrict__ w0,
                            ushort* __restrict__ dst) {
    const int N = 288 * 512;
    for (int idx = blockIdx.x * blockDim.x + threadIdx.x; idx < N; idx += gridDim.x * blockDim.x) {
        int k = idx & 31, oc = (idx >> 5) & 15;
        int blk = idx >> 9;
        int tap = blk % 9, r = blk / 9;
        int half = r & 1; r >>= 1;
        int mat = r & 3; int ocbI = r >> 2;
        int OC = ocbI * 16 + oc, ic = half * 32 + k;
        const float* w = (mat < 2) ? w1 : w0;
        float v = w[((size_t)OC * 64 + ic) * 9 + tap];
        __hip_bfloat16 h16 = __float2bfloat16(v);
        if (mat & 1) { float rr = v - __bfloat162float(h16); h16 = __float2bfloat16(rr); }
        dst[idx] = *(ushort*)&h16;
    }
}

// ---------------- A-frag prep for gamma/beta ------
// blk = ((mat*2+hl)*4 + ocbI)*36 + icq*9 + tap ; mat 0=gamma 1=beta
__global__ void prep_wfrag(const float* __restrict__ wg, const float* __restrict__ wb2,
                           ushort* __restrict__ dst) {
    const int N = 16 * 36 * 512;
    for (int idx = blockIdx.x * blockDim.x + threadIdx.x; idx < N; idx += gridDim.x * blockDim.x) {
        int k = idx & 31, oc = (idx >> 5) & 15;
        int blk = idx >> 9;
        int ks = blk % 36, q = blk / 36;
        int ocbI = q & 3, q4 = q >> 2, hl = q4 & 1, mat = q4 >> 1;
        int icq = ks / 9, tap = ks % 9;
        int OC = ocbI * 16 + oc, ic = icq * 32 + k;
        const float* w = mat ? wb2 : wg;
        float v = w[((size_t)OC * 128 + ic) * 9 + tap];
        __hip_bfloat16 h16 = __float2bfloat16(v);
        if (hl) { float r = v - __bfloat162float(h16); h16 = __float2bfloat16(r); }
        dst[idx] = *(ushort*)&h16;
    }
}

// ---------------- fused MFMA: conv1(lrelu+pool) AND conv_c0 stats -----------
// B-fragments read per-lane from global (no LDS tile, no barriers in K-loop)
__global__ __launch_bounds__(256) void conv1c0_kernel(
    const char* __restrict__ fincl, const ushort* __restrict__ wfC,
    const float* __restrict__ bias1, const float* __restrict__ bias0,
    const int* __restrict__ seg, const float* __restrict__ bg,
    const float* __restrict__ mask, const float* __restrict__ zrow,
    float* __restrict__ sums, int* __restrict__ cnts, float* __restrict__ statacc,
    int batch0)
{
    __shared__ float s35[LABELS * 16];
    __shared__ int   c35[LABELS];
    __shared__ float wsum[4][16][2];

    const int t = threadIdx.x, h = blockIdx.y, bxI = blockIdx.x, ocb = bxI * 16;
    const int z = blockIdx.z, b = batch0 + z;
    const int l = t & 63, wv = t >> 6;
    const char* clb = fincl + (size_t)z * CLB;
    const char* zp = (const char*)zrow;
    const int loff = ((l & 15) << 6) + ((l >> 4) << 4);
    const int myoct = l >> 4;
    const int pxb = wv * 64 + (l & 15);

    for (int i = t; i < LABELS * 16; i += 256) s35[i] = 0.f;
    if (t < LABELS) c35[t] = 0;

    f32x4 a1[4], a0[4];
#pragma unroll
    for (int j = 0; j < 4; j++) {
        int c = ocb + ((l >> 4) << 2) + j;
        float v1 = bias1[c], v0 = bias0[c];
#pragma unroll
        for (int pt = 0; pt < 4; pt++) { a1[pt][j] = v1; a0[pt][j] = v0; }
    }

#pragma unroll
    for (int icq = 0; icq < 4; icq++) {
        const int jo0 = icq * 4;
#pragma unroll
        for (int tap = 0; tap < 9; tap++) {
            const int ky = tap / 3, kx = tap % 3;
            const int gh = h + ky - 1;
            const bool rok = (unsigned)gh < Hh;
            const char* rowp = clb + ((size_t)gh * 16 + jo0 + myoct) * (256 * 16);
            if (icq < 2) {
                bf16x8 A0 = aread(wfC, blkC(bxI, 0, icq, tap), loff);   // w1 hi
                bf16x8 A1 = aread(wfC, blkC(bxI, 1, icq, tap), loff);   // w1 lo
                bf16x8 A2 = aread(wfC, blkC(bxI, 2, icq, tap), loff);   // w0 hi
                bf16x8 A3 = aread(wfC, blkC(bxI, 3, icq, tap), loff);   // w0 lo
#pragma unroll
                for (int pt = 0; pt < 4; pt++) {
                    bf16x8 B = breadG(rowp, rok, pxb + pt * 16 + kx - 1, zp);
                    a1[pt] = MFMA16(A0, B, a1[pt], 0, 0, 0);
                    a1[pt] = MFMA16(A1, B, a1[pt], 0, 0, 0);
                    a0[pt] = MFMA16(A2, B, a0[pt], 0, 0, 0);
                    a0[pt] = MFMA16(A3, B, a0[pt], 0, 0, 0);
                }
            } else {
                bf16x8 A0 = aread(wfC, blkC(bxI, 0, icq - 2, tap), loff); // w1 hi on lo-chs
                bf16x8 A2 = aread(wfC, blkC(bxI, 2, icq - 2, tap), loff); // w0 hi on lo-chs
#pragma unroll
                for (int pt = 0; pt < 4; pt++) {
                    bf16x8 B = breadG(rowp, rok, pxb + pt * 16 + kx - 1, zp);
                    a1[pt] = MFMA16(A0, B, a1[pt], 0, 0, 0);
                    a0[pt] = MFMA16(A2, B, a0[pt], 0, 0, 0);
                }
            }
        }
    }

    // ---- conv1 branch: lrelu + masked class pooling ----
    // each pixel is held by 4 lanes (one per oc-group l>>4); count gated to l<16.
    const int*   segh = seg  + (size_t)b * HW + (size_t)h * 256;
    const float* bgh  = bg   + (size_t)b * HW + (size_t)h * 256;
    const float* mh   = mask + (size_t)b * HW + (size_t)h * 256;
#pragma unroll
    for (int pt = 0; pt < 4; pt++) {
        int px = wv * 64 + pt * 16 + (l & 15);
        int lab = segh[px];
        bool m = (bgh[px] != 0.f) && (mh[px] == 0.f);
        if (m) {
#pragma unroll
            for (int j = 0; j < 4; j++) {
                float o = a1[pt][j];
                o = (o >= 0.f) ? o : 0.2f * o;
                atomicAdd(&s35[lab * 16 + ((l >> 4) << 2) + j], o);
            }
            if (bxI == 0 && l < 16) atomicAdd(&c35[lab], 1);
        }
    }
    // ---- conv_c0 branch: per-channel sum / sumsq ----
#pragma unroll
    for (int j = 0; j < 4; j++) {
        float s = a0[0][j] + a0[1][j] + a0[2][j] + a0[3][j];
        float ss = a0[0][j]*a0[0][j] + a0[1][j]*a0[1][j] + a0[2][j]*a0[2][j] + a0[3][j]*a0[3][j];
#pragma unroll
        for (int off = 1; off < 16; off <<= 1) { s += __shfl_xor(s, off); ss += __shfl_xor(ss, off); }
        if ((l & 15) == 0) { wsum[wv][((l >> 4) << 2) + j][0] = s; wsum[wv][((l >> 4) << 2) + j][1] = ss; }
    }
    __syncthreads();
    for (int i = t; i < LABELS * 16; i += 256) {
        float v = s35[i];
        if (v != 0.f) {
            int s = i >> 4, oc = i & 15;
            atomicAdd(&sums[((size_t)b * LABELS + s) * SDIM + ocb + oc], v);
        }
    }
    if (bxI == 0 && t < LABELS && c35[t] > 0) atomicAdd(&cnts[b * LABELS + t], c35[t]);
    if (t < 16) {
        float S = 0.f, SS = 0.f;
#pragma unroll
        for (int w2 = 0; w2 < 4; w2++) { S += wsum[w2][t][0]; SS += wsum[w2][t][1]; }
        atomicAdd(&statacc[(size_t)(b * SDIM + ocb + t) * 2 + 0], S);
        atomicAdd(&statacc[(size_t)(b * SDIM + ocb + t) * 2 + 1], SS);
    }
}

// ---------------- codes = keep * where(cnt>0, sums/cnt, 0) ------------------
__global__ void codes_kernel(const float* __restrict__ sums, const int* __restrict__ cnts,
                             float* __restrict__ codes) {
    int idx = blockIdx.x * blockDim.x + threadIdx.x;
    if (idx >= Bn * LABELS * SDIM) return;
    int s  = (idx >> 6) % LABELS;
    int bs = idx >> 6;
    int cnt = cnts[bs];
    bool keep = !(s >= 24 && s <= 33);
    codes[idx] = (cnt > 0 && keep) ? sums[idx] / (float)cnt : 0.f;
}

__global__ void finalize_stats(const float* __restrict__ statacc,
                               float* __restrict__ mu, float* __restrict__ rsig) {
    int i = blockIdx.x * blockDim.x + threadIdx.x;
    if (i >= Bn * SDIM) return;
    float S = statacc[2 * i], SS = statacc[2 * i + 1];
    float m = S / (float)HW;
    float v = SS / (float)HW - m * m;
    mu[i] = m;
    rsig[i] = rsqrtf(v + 1e-5f);
}

// ---------------- conv_sh lookup table ------------------------------------
__global__ void make_T(const float* __restrict__ codes, const float* __restrict__ w_sh,
                       float* __restrict__ T) {
    __shared__ float cod[64];
    const int lab = blockIdx.x, b = blockIdx.y, t = threadIdx.x;
    if (t < 64) cod[t] = codes[((size_t)b * LABELS + lab) * SDIM + t];
    __syncthreads();
    for (int i = t; i < NHID * 9; i += 256) {
        int oc = i / 9, tap = i % 9;
        float s = w_sh[((size_t)oc * 99 + 64 + lab) * 9 + tap];
#pragma unroll
        for (int ic = 0; ic < 64; ic++)
            s = fmaf(w_sh[((size_t)oc * 99 + ic) * 9 + tap], cod[ic], s);
        T[((size_t)b * NHID + oc) * (LABELS * 9) + lab * 9 + tap] = s;
    }
}

// ---------------- conv_sh via T-table; actv plane layout [h][oct][px] -------
__global__ __launch_bounds__(256) void conv_sh_kernel(
    const int* __restrict__ seg, const float* __restrict__ bg,
    const float* __restrict__ T, const float* __restrict__ bf,
    char* __restrict__ actv, int batch0)
{
    __shared__ float Ts[16 * 316];
    __shared__ int   labr[3 * 260];
    __shared__ float bgr[3 * 260];

    const int t = threadIdx.x, h = blockIdx.y, bxI = blockIdx.x, ocb = bxI * 16;
    const int z = blockIdx.z, b = batch0 + z;
    const int*   seg_b = seg + (size_t)b * HW;
    const float* bg_b  = bg + (size_t)b * HW;
    char* actv_b = actv + (size_t)z * CLB;

    const float* Tb = T + ((size_t)b * NHID + ocb) * 315;
    for (int i = t; i < 16 * 315; i += 256)
        Ts[(i / 315) * 316 + (i % 315)] = Tb[i];

    for (int i = t; i < 3 * 258; i += 256) {
        int r = i / 258, x = i % 258;
        int gh = h + r - 1, gw = x - 1;
        int lab = 0; float bgv = 0.f;
        if ((unsigned)gh < Hh && (unsigned)gw < Ww) { lab = seg_b[gh * Ww + gw]; bgv = bg_b[gh * Ww + gw]; }
        labr[r * 260 + x] = lab; bgr[r * 260 + x] = bgv;
    }

    float acc[16];
#pragma unroll
    for (int oc = 0; oc < 16; oc++) acc[oc] = bf[ocb + oc];
    __syncthreads();

#pragma unroll
    for (int ky = 0; ky < 3; ky++) {
#pragma unroll
        for (int kx = 0; kx < 3; kx++) {
            int lab  = labr[ky * 260 + t + kx];
            float bgv = bgr[ky * 260 + t + kx];
            int off = lab * 9 + ky * 3 + kx;
#pragma unroll
            for (int oc = 0; oc < 16; oc++)
                acc[oc] = fmaf(Ts[oc * 316 + off], bgv, acc[oc]);
        }
    }

    // relu + pack 16 oc -> octets 2*bxI, 2*bxI+1 at px=t (coalesced 16B stores)
    uint pk[8];
#pragma unroll
    for (int i = 0; i < 8; i++) {
        float lo = fmaxf(acc[2 * i], 0.f), hi = fmaxf(acc[2 * i + 1], 0.f);
        __hip_bfloat16 l16 = __float2bfloat16(lo), h16 = __float2bfloat16(hi);
        pk[i] = (uint)*(ushort*)&l16 | ((uint)*(ushort*)&h16 << 16);
    }
    *(uint4*)(actv_b + (((size_t)h * 16 + bxI * 2)     * 256 + t) * 16) = make_uint4(pk[0], pk[1], pk[2], pk[3]);
    *(uint4*)(actv_b + (((size_t)h * 16 + bxI * 2 + 1) * 256 + t) * 16) = make_uint4(pk[4], pk[5], pk[6], pk[7]);
}

// ---------------- fused: dx (MFMA) + gamma/beta (MFMA) + IN + lrelu ---------
// B-fragments read per-lane from global (no LDS, no barriers)
__global__ __launch_bounds__(256) void final_fused_kernel(
    const char* __restrict__ fincl, const char* __restrict__ actv,
    const ushort* __restrict__ wfC, const ushort* __restrict__ wfGB,
    const float* __restrict__ bc0, const float* __restrict__ bg2, const float* __restrict__ bb2,
    const float* __restrict__ mu, const float* __restrict__ rsig,
    const float* __restrict__ zrow, float* __restrict__ out, int batch0)
{
    const int t = threadIdx.x, h = blockIdx.y, bxI = blockIdx.x, ocb = bxI * 16;
    const int z = blockIdx.z, b = batch0 + z;
    const int l = t & 63, wv = t >> 6;
    const char* clb = fincl + (size_t)z * CLB;
    const char* avb = actv + (size_t)z * CLB;
    const char* zp = (const char*)zrow;
    const int loff = ((l & 15) << 6) + ((l >> 4) << 4);
    const int myoct = l >> 4;
    const int pxb = wv * 64 + (l & 15);

    f32x4 ad[4], ag[4], ab2[4];
#pragma unroll
    for (int j = 0; j < 4; j++) {
        int c = ocb + ((l >> 4) << 2) + j;
        float vd = bc0[c], vg = bg2[c], vb = bb2[c];
#pragma unroll
        for (int pt = 0; pt < 4; pt++) { ad[pt][j] = vd; ag[pt][j] = vg; ab2[pt][j] = vb; }
    }

#pragma unroll
    for (int c8 = 0; c8 < 8; c8++) {
        const bool isfin = (c8 < 4);
        const int icq = isfin ? c8 : c8 - 4;
        const char* tb = isfin ? clb : avb;
        const int jo0 = icq * 4;
#pragma unroll
        for (int tap = 0; tap < 9; tap++) {
            const int ky = tap / 3, kx = tap % 3;
            const int gh = h + ky - 1;
            const bool rok = (unsigned)gh < Hh;
            const char* rowp = tb + ((size_t)gh * 16 + jo0 + myoct) * (256 * 16);
            if (isfin) {
                if (icq < 2) {
                    bf16x8 A2 = aread(wfC, blkC(bxI, 2, icq, tap), loff);
                    bf16x8 A3 = aread(wfC, blkC(bxI, 3, icq, tap), loff);
#pragma unroll
                    for (int pt = 0; pt < 4; pt++) {
                        bf16x8 B = breadG(rowp, rok, pxb + pt * 16 + kx - 1, zp);
                        ad[pt] = MFMA16(A2, B, ad[pt], 0, 0, 0);
                        ad[pt] = MFMA16(A3, B, ad[pt], 0, 0, 0);
                    }
                } else {
                    bf16x8 A2 = aread(wfC, blkC(bxI, 2, icq - 2, tap), loff);
#pragma unroll
                    for (int pt = 0; pt < 4; pt++) {
                        bf16x8 B = breadG(rowp, rok, pxb + pt * 16 + kx - 1, zp);
                        ad[pt] = MFMA16(A2, B, ad[pt], 0, 0, 0);
                    }
                }
            } else {
                const int ks = icq * 9 + tap;
                bf16x8 agh = aread(wfGB, (0 * 4 + bxI) * 36 + ks, loff);
                bf16x8 agl = aread(wfGB, (1 * 4 + bxI) * 36 + ks, loff);
                bf16x8 abh = aread(wfGB, (2 * 4 + bxI) * 36 + ks, loff);
                bf16x8 abl = aread(wfGB, (3 * 4 + bxI) * 36 + ks, loff);
#pragma unroll
                for (int pt = 0; pt < 4; pt++) {
                    bf16x8 B = breadG(rowp, rok, pxb + pt * 16 + kx - 1, zp);
                    ag[pt]  = MFMA16(agh, B, ag[pt], 0, 0, 0);
                    ag[pt]  = MFMA16(agl, B, ag[pt], 0, 0, 0);
                    ab2[pt] = MFMA16(abh, B, ab2[pt], 0, 0, 0);
                    ab2[pt] = MFMA16(abl, B, ab2[pt], 0, 0, 0);
                }
            }
        }
    }

    // ---- epilogue: dx in the same C-layout as gamma/beta ----
    const float* mu_b = mu + b * SDIM;
    const float* rs_b = rsig + b * SDIM;
    float* out_b = out + (size_t)b * SDIM * HW;
    float muj[4], rsj[4];
#pragma unroll
    for (int j = 0; j < 4; j++) { int c = ocb + ((l >> 4) << 2) + j; muj[j] = mu_b[c]; rsj[j] = rs_b[c]; }
#pragma unroll
    for (int pt = 0; pt < 4; pt++) {
        int px = wv * 64 + pt * 16 + (l & 15);
#pragma unroll
        for (int j = 0; j < 4; j++) {
            int cl = ((l >> 4) << 2) + j;
            float nrm = (ad[pt][j] - muj[j]) * rsj[j];
            float o = nrm * (1.f + ag[pt][j]) + ab2[pt][j];
            o = (o >= 0.f) ? o : 0.2f * o;
            out_b[(size_t)(ocb + cl) * HW + (size_t)h * 256 + px] = o;
        }
    }
}

// ===========================================================================
extern "C" void kernel_launch(void* const* d_in, const int* in_sizes, int n_in,
                              void* d_out, int out_size, void* d_ws, size_t ws_size,
                              hipStream_t stream) {
    const float* featmap_in = (const float*)d_in[0];
    const int*   seg        = (const int*)d_in[1];
    const float* bg         = (const float*)d_in[2];
    const float* mask       = (const float*)d_in[3];
    const float* w_conv     = (const float*)d_in[4];
    const float* b_conv     = (const float*)d_in[5];
    const float* w_c0       = (const float*)d_in[6];
    const float* b_c0       = (const float*)d_in[7];
    const float* w_sh       = (const float*)d_in[8];
    const float* b_sh       = (const float*)d_in[9];
    const float* w_g        = (const float*)d_in[10];
    const float* b_g        = (const float*)d_in[11];
    const float* w_b        = (const float*)d_in[12];
    const float* b_b        = (const float*)d_in[13];
    float* out = (float*)d_out;

    // ---- workspace arena ----
    char* ws = (char*)d_ws;
    size_t o = 0;
    auto alloc = [&](size_t bytes) -> char* {
        size_t r = o; o = (o + bytes + 255) & ~(size_t)255; return ws + r;
    };
    ushort* wfC     = (ushort*)alloc((size_t)288 * 512 * 2);        // 294912 B
    ushort* wfGB    = (ushort*)alloc((size_t)16 * 36 * 512 * 2);    // 589824 B
    float*  Ttab    = (float*)alloc((size_t)Bn * NHID * LABELS * 9 * 4);
    float*  sums    = (float*)alloc((size_t)Bn * LABELS * SDIM * 4);
    int*    cnts    = (int*)alloc((size_t)Bn * LABELS * 4);
    float*  codes   = (float*)alloc((size_t)Bn * LABELS * SDIM * 4);
    float*  statacc = (float*)alloc((size_t)Bn * SDIM * 2 * 4);
    float*  mu      = (float*)alloc((size_t)Bn * SDIM * 4);
    float*  rsig    = (float*)alloc((size_t)Bn * SDIM * 4);
    float*  zrow    = (float*)alloc(1024);

    size_t rem = (ws_size > o) ? ws_size - o : 0;
    int tier = (rem >= 2 * CLB * Bn + 1024) ? 1 : (rem >= CLB * Bn + CLB + 1024) ? 2 : 3;
    char* fincl; char* actvc;
    if (tier == 1)      { fincl = alloc(CLB * Bn); actvc = alloc(CLB * Bn); }
    else if (tier == 2) { fincl = alloc(CLB * Bn); actvc = alloc(CLB); }
    else                { fincl = alloc(CLB);      actvc = alloc(CLB); }

    prep_wfragC<<<144, 256, 0, stream>>>(w_conv, w_c0, wfC);
    prep_wfrag<<<288, 256, 0, stream>>>(w_g, w_b, wfGB);

    hipMemsetAsync(sums, 0, (size_t)Bn * LABELS * SDIM * 4, stream);
    hipMemsetAsync(cnts, 0, (size_t)Bn * LABELS * 4, stream);
    hipMemsetAsync(statacc, 0, (size_t)Bn * SDIM * 2 * 4, stream);
    hipMemsetAsync(zrow, 0, 1024, stream);

    if (tier <= 2) {
        repack_fin<<<dim3(Hh, Bn), 256, 0, stream>>>(featmap_in, fincl, 0);
        conv1c0_kernel<<<dim3(4, Hh, Bn), 256, 0, stream>>>(
            fincl, wfC, b_conv, b_c0, seg, bg, mask, zrow, sums, cnts, statacc, 0);
    } else {
        for (int b = 0; b < Bn; b++) {
            repack_fin<<<dim3(Hh, 1), 256, 0, stream>>>(featmap_in, fincl, b);
            conv1c0_kernel<<<dim3(4, Hh, 1), 256, 0, stream>>>(
                fincl, wfC, b_conv, b_c0, seg, bg, mask, zrow, sums, cnts, statacc, b);
        }
    }
    codes_kernel<<<(Bn * LABELS * SDIM + 255) / 256, 256, 0, stream>>>(sums, cnts, codes);
    finalize_stats<<<2, 256, 0, stream>>>(statacc, mu, rsig);
    make_T<<<dim3(LABELS, Bn), 256, 0, stream>>>(codes, w_sh, Ttab);

    if (tier == 1) {
        conv_sh_kernel<<<dim3(8, Hh, Bn), 256, 0, stream>>>(seg, bg, Ttab, b_sh, actvc, 0);
        final_fused_kernel<<<dim3(4, Hh, Bn), 256, 0, stream>>>(
            fincl, actvc, wfC, wfGB, b_c0, b_g, b_b, mu, rsig, zrow, out, 0);
    } else if (tier == 2) {
        for (int b = 0; b < Bn; b++) {
            conv_sh_kernel<<<dim3(8, Hh, 1), 256, 0, stream>>>(seg, bg, Ttab, b_sh, actvc, b);
            final_fused_kernel<<<dim3(4, Hh, 1), 256, 0, stream>>>(
                fincl + (size_t)b * CLB, actvc, wfC, wfGB, b_c0, b_g, b_b, mu, rsig, zrow, out, b);
        }
    } else {
        for (int b = 0; b < Bn; b++) {
            repack_fin<<<dim3(Hh, 1), 256, 0, stream>>>(featmap_in, fincl, b);
            conv_sh_kernel<<<dim3(8, Hh, 1), 256, 0, stream>>>(seg, bg, Ttab, b_sh, actvc, b);
            final_fused_kernel<<<dim3(4, Hh, 1), 256, 0, stream>>>(
                fincl, actvc, wfC, wfGB, b_c0, b_g, b_b, mu, rsig, zrow, out, b);
        }
    }
}